// Round 15
// baseline (793.220 us; speedup 1.0000x reference)
//
#include <hip/hip_runtime.h>
#include <hip/hip_bf16.h>
#include <stdint.h>

#define B_   128
#define LT   256
#define LI   576
#define HD   1024
#define SMOOTHF 9.0f
#define EPSF 1e-8f

typedef __bf16 bf16x8 __attribute__((ext_vector_type(8)));
typedef float  f32x4  __attribute__((ext_vector_type(4)));

__device__ inline ushort f2b(float f) {
  uint32_t u = __float_as_uint(f);
  u += 0x7FFFu + ((u >> 16) & 1u);   // RNE
  return (ushort)(u >> 16);
}
__device__ inline float b2f(ushort u) {
  return __uint_as_float((uint32_t)u << 16);
}

// async global->LDS, 16B per lane. LDS dest is wave-uniform base + lane*16.
__device__ __forceinline__ void gload_lds16(const ushort* g, ushort* l) {
  __builtin_amdgcn_global_load_lds(
      (const __attribute__((address_space(1))) unsigned int*)(g),
      (__attribute__((address_space(3))) unsigned int*)(l),
      16, 0, 0);
}

// ---------------- fp32 -> bf16, three ranges per launch ----------------
__global__ __launch_bounds__(256) void cvt3_bf16_kernel(
    const float* __restrict__ inA, ushort* __restrict__ outA, int n4A,
    const float* __restrict__ inB, ushort* __restrict__ outB, int n4B,
    const float* __restrict__ inC, ushort* __restrict__ outC, int n4C) {
  int idx = blockIdx.x * blockDim.x + threadIdx.x;
  int stride = gridDim.x * blockDim.x;
  int total = n4A + n4B + n4C;
  for (int i = idx; i < total; i += stride) {
    const float* in; ushort* out; int j;
    if (i < n4A)            { in = inA; out = outA; j = i; }
    else if (i < n4A + n4B) { in = inB; out = outB; j = i - n4A; }
    else                    { in = inC; out = outC; j = i - n4A - n4B; }
    float4 v = reinterpret_cast<const float4*>(in)[j];
    ushort4 o = make_ushort4(f2b(v.x), f2b(v.y), f2b(v.z), f2b(v.w));
    reinterpret_cast<ushort4*>(out)[j] = o;
  }
}

// ---------------- fp32 -> bf16 normal + transposed copies (r4-verified) ------
__global__ __launch_bounds__(256) void cvtT_kernel(
    const float* __restrict__ in, ushort* __restrict__ outN,
    ushort* __restrict__ outT, int R) {
  __shared__ float T[64][65];
  int b = blockIdx.y;
  int nrt = R >> 6;
  int rt = blockIdx.x % nrt, ct = blockIdx.x / nrt;
  int r0 = rt << 6, c0 = ct << 6;
  const float* src = in + ((size_t)b * R + r0) * HD + c0;
  ushort* dN = outN + ((size_t)b * R + r0) * HD + c0;
  ushort* dT = outT + ((size_t)b * HD + c0) * R + r0;
  int tid = threadIdx.x;
  #pragma unroll
  for (int j = 0; j < 4; ++j) {
    int q = tid + j * 256;
    int row = q >> 4;
    int c4  = (q & 15) << 2;
    float4 v = *reinterpret_cast<const float4*>(src + (size_t)row * HD + c4);
    reinterpret_cast<ushort4*>(dN + (size_t)row * HD)[c4 >> 2] =
        make_ushort4(f2b(v.x), f2b(v.y), f2b(v.z), f2b(v.w));
    T[c4 + 0][row] = v.x;
    T[c4 + 1][row] = v.y;
    T[c4 + 2][row] = v.z;
    T[c4 + 3][row] = v.w;
  }
  __syncthreads();
  #pragma unroll
  for (int j = 0; j < 4; ++j) {
    int q = tid + j * 256;
    int crow = q >> 4;
    int r4   = (q & 15) << 2;
    ushort4 o = make_ushort4(f2b(T[crow][r4]), f2b(T[crow][r4 + 1]),
                             f2b(T[crow][r4 + 2]), f2b(T[crow][r4 + 3]));
    reinterpret_cast<ushort4*>(dT + (size_t)crow * R)[r4 >> 2] = o;
  }
}

// ---------------- 256x256, BK=64, 8-phase counted-vmcnt + LDS swizzle --------
// r12/r13/r14-verified schedule (race-clean; odd-NT tail HW-verified).
// Always MPRED (clamp is a no-op v_min when M % 256 == 0) so multiple GEMM
// shapes share ONE instantiation; param-select wrappers keep ONE body per
// __global__ kernel (r13 lesson: two inlined bodies thrash the I$).
template<bool OUT_BF16, bool RELU_BIAS>
__device__ __forceinline__ void gemm256p8_body(
    ushort* lds, int bid,
    const ushort* __restrict__ A, const ushort* __restrict__ Bm,
    const float* __restrict__ bias, void* __restrict__ C,
    int M, int N, int K, long sA, long sB, long sC,
    int lda, int ldb, int ldc)
{
  const int ntn = N >> 8;
  const int ntm = (M + 255) >> 8;
  const int tpb = ntm * ntn;
  const int b   = bid / tpb;
  const int tl  = bid - b * tpb;
  const int m0 = (tl / ntn) << 8;
  const int n0 = (tl % ntn) << 8;

  const int t    = threadIdx.x;
  const int lane = t & 63, w = t >> 6;
  const int wr = w >> 2, wc = w & 3;          // quadrant-local: 2Mx4N waves
  const int r16 = lane & 15, g = lane >> 4;

  const ushort* gA0 = A  + (size_t)b * sA;
  const ushort* gB0 = Bm + (size_t)b * sB + (size_t)n0 * ldb;

  f32x4 acc[2][2][4][2] = {};
  const int NT  = K >> 6;
  const int NIT = NT >> 1;

  auto STAGEH = [&](int mat, int h, int kt) {
    ushort* dst = lds + (kt & 1) * 32768 + mat * 16384 + h * 8192 + t * 8;
    int scol = (((t & 7) ^ ((t >> 3) & 7)) << 3) + kt * 64;   // pre-swizzled src
    #pragma unroll
    for (int q = 0; q < 2; ++q) {
      int row = h * 128 + q * 64 + (t >> 3);
      const ushort* src;
      if (!mat) {
        int ar = m0 + row;
        ar = ar < M ? ar : M - 1;
        src = gA0 + (size_t)ar * lda + scol;
      } else {
        src = gB0 + (size_t)row * ldb + scol;
      }
      gload_lds16(src, dst + q * 4096);
    }
  };

  // prologue: T0 complete + T1.A0,B0   (12 loads; vmcnt(4) -> T0 landed)
  STAGEH(0, 0, 0); STAGEH(1, 0, 0); STAGEH(0, 1, 0); STAGEH(1, 1, 0);
  STAGEH(0, 0, 1); STAGEH(1, 0, 1);
  asm volatile("s_waitcnt vmcnt(4)" ::: "memory");
  __builtin_amdgcn_sched_barrier(0);
  __builtin_amdgcn_s_barrier();
  __builtin_amdgcn_sched_barrier(0);

  const int sw = (r16 & 7) << 3;              // per-lane read swizzle

  for (int it = 0; it < NIT; ++it) {
    const int T0 = 2 * it;
    const bool lastit = (it == NIT - 1);
    #pragma unroll
    for (int p = 0; p < 8; ++p) {
      const int d  = p >> 2;
      const int qm = (p >> 1) & 1, qn = p & 1;
      const ushort* Ah = lds + d * 32768 + qm * 8192;
      const ushort* Bh = lds + d * 32768 + 16384 + qn * 8192;
      bf16x8 af[2][4], bfr[2][2];
      #pragma unroll
      for (int kk = 0; kk < 2; ++kk) {
        #pragma unroll
        for (int f = 0; f < 4; ++f)
          af[kk][f] = *reinterpret_cast<const bf16x8*>(
              Ah + (wr * 64 + f * 16 + r16) * 64 + ((kk * 32 + g * 8) ^ sw));
        #pragma unroll
        for (int c = 0; c < 2; ++c)
          bfr[kk][c] = *reinterpret_cast<const bf16x8*>(
              Bh + (wc * 32 + c * 16 + r16) * 64 + ((kk * 32 + g * 8) ^ sw));
      }
      {
        const int toff[8] = {1, 1, 2, 2, 2, 2, 3, 3};
        const int tmat[8] = {0, 1, 0, 1, 0, 1, 0, 1};
        const int thlf[8] = {1, 1, 0, 0, 1, 1, 0, 0};
        int kt = T0 + toff[p];
        if (kt < NT) STAGEH(tmat[p], thlf[p], kt);
      }
      if (p == 3 || p == 7) {
        if (lastit) { asm volatile("s_waitcnt vmcnt(0)" ::: "memory"); }
        else        { asm volatile("s_waitcnt vmcnt(4)" ::: "memory"); }
      }
      __builtin_amdgcn_sched_barrier(0);
      __builtin_amdgcn_s_barrier();
      __builtin_amdgcn_sched_barrier(0);
      __builtin_amdgcn_s_setprio(1);
      #pragma unroll
      for (int kk = 0; kk < 2; ++kk)
        #pragma unroll
        for (int f = 0; f < 4; ++f)
          #pragma unroll
          for (int c = 0; c < 2; ++c)
            acc[qm][qn][f][c] = __builtin_amdgcn_mfma_f32_16x16x32_bf16(
                af[kk][f], bfr[kk][c], acc[qm][qn][f][c], 0, 0, 0);
      __builtin_amdgcn_s_setprio(0);
      __builtin_amdgcn_sched_barrier(0);
      __builtin_amdgcn_s_barrier();
      __builtin_amdgcn_sched_barrier(0);
    }
  }

  // ---- odd-NT tail: last K-tile staged+drained at lastit; reads only ----
  if (NT & 1) {
    const int d = (NT - 1) & 1;
    const ushort* base = lds + d * 32768;
    #pragma unroll
    for (int p = 0; p < 4; ++p) {
      const int qm = p >> 1, qn = p & 1;
      const ushort* Ah = base + qm * 8192;
      const ushort* Bh = base + 16384 + qn * 8192;
      bf16x8 af[2][4], bfr[2][2];
      #pragma unroll
      for (int kk = 0; kk < 2; ++kk) {
        #pragma unroll
        for (int f = 0; f < 4; ++f)
          af[kk][f] = *reinterpret_cast<const bf16x8*>(
              Ah + (wr * 64 + f * 16 + r16) * 64 + ((kk * 32 + g * 8) ^ sw));
        #pragma unroll
        for (int c = 0; c < 2; ++c)
          bfr[kk][c] = *reinterpret_cast<const bf16x8*>(
              Bh + (wc * 32 + c * 16 + r16) * 64 + ((kk * 32 + g * 8) ^ sw));
      }
      #pragma unroll
      for (int kk = 0; kk < 2; ++kk)
        #pragma unroll
        for (int f = 0; f < 4; ++f)
          #pragma unroll
          for (int c = 0; c < 2; ++c)
            acc[qm][qn][f][c] = __builtin_amdgcn_mfma_f32_16x16x32_bf16(
                af[kk][f], bfr[kk][c], acc[qm][qn][f][c], 0, 0, 0);
    }
  }

  // epilogue: C/D layout col=lane&15, row=(lane>>4)*4+reg [m89-verified]
  #pragma unroll
  for (int qm = 0; qm < 2; ++qm)
    #pragma unroll
    for (int qn = 0; qn < 2; ++qn)
      #pragma unroll
      for (int f = 0; f < 4; ++f) {
        int rbase = m0 + qm * 128 + wr * 64 + f * 16 + g * 4;
        #pragma unroll
        for (int rr = 0; rr < 4; ++rr) {
          if (rbase + rr >= M) continue;
          size_t off0 = (size_t)b * sC + (size_t)(rbase + rr) * ldc
                      + n0 + qn * 128 + wc * 32;
          #pragma unroll
          for (int c = 0; c < 2; ++c) {
            int col = c * 16 + r16;
            float v = acc[qm][qn][f][c][rr];
            if (RELU_BIAS) v = fmaxf(v + bias[n0 + qn * 128 + wc * 32 + col], 0.0f);
            if (OUT_BF16) reinterpret_cast<ushort*>(C)[off0 + col] = f2b(v);
            else          reinterpret_cast<float*>(C)[off0 + col]  = v;
          }
        }
      }
}

// ---- param-select wrappers: ONE inlined body each (r13 I$ lesson) ----------
// G (384) + Pt (512): share N=256, K=1024, lda/ldb/ldc.
__global__ __launch_bounds__(512, 2) void g_pt_kernel(
    const ushort* __restrict__ img_b, const ushort* __restrict__ txt_b,
    const ushort* __restrict__ Wi_b, ushort* __restrict__ Gm_b,
    ushort* __restrict__ Pt) {
  extern __shared__ ushort lds[];
  int bid = blockIdx.x;
  { int cpx = gridDim.x >> 3; bid = (bid & 7) * cpx + (bid >> 3); }
  bool isG = bid < 384;
  gemm256p8_body<true, false>(lds,
      isG ? bid : bid - 384,
      isG ? img_b : Wi_b, txt_b, nullptr,
      isG ? (void*)Gm_b : (void*)Pt,
      isG ? LI : HD, LT, HD,
      isG ? (long)LI * HD : 0L, (long)LT * HD,
      isG ? (long)LI * LT : (long)HD * LT,
      HD, HD, LT);
}

// AV1: txtAE = attn_img . img  (NT via imgT, K=576 odd-NT)
__global__ __launch_bounds__(512, 2) void av1_kernel(
    const ushort* __restrict__ ai_b, const ushort* __restrict__ imgT,
    ushort* __restrict__ txtAE) {
  extern __shared__ ushort lds[];
  int bid = blockIdx.x;
  { int cpx = gridDim.x >> 3; bid = (bid & 7) * cpx + (bid >> 3); }
  gemm256p8_body<true, false>(lds, bid, ai_b, imgT, nullptr, txtAE,
      LT, HD, LI, (long)LT * LI, (long)HD * LI, (long)LT * HD, LI, LI, HD);
}

// FC1 (512) + out_img (1536): share N=1024, ldc=HD.
__global__ __launch_bounds__(512, 2) void fc_oi_kernel(
    const ushort* __restrict__ txtAE, const ushort* __restrict__ Wt_b,
    const float* __restrict__ b_txt, float* __restrict__ out_txt,
    const ushort* __restrict__ at_b, const ushort* __restrict__ Pt,
    const float* __restrict__ b_img, float* __restrict__ out_img) {
  extern __shared__ ushort lds[];
  int bid = blockIdx.x;
  { int cpx = gridDim.x >> 3; bid = (bid & 7) * cpx + (bid >> 3); }
  bool isFC = bid < 512;
  gemm256p8_body<false, true>(lds,
      isFC ? bid : bid - 512,
      isFC ? txtAE : at_b, isFC ? Wt_b : Pt, isFC ? b_txt : b_img,
      isFC ? (void*)out_txt : (void*)out_img,
      isFC ? B_ * LT : LI, HD, isFC ? HD : LT,
      isFC ? 0L : (long)LI * LT, isFC ? 0L : (long)HD * LT,
      isFC ? 0L : (long)LI * HD,
      isFC ? HD : LT, isFC ? HD : LT, HD);
}

// ---------------- fused pass1: rowsums + col partials + attn_img stats --------
__global__ __launch_bounds__(256) void gstats_kernel(
    const ushort* __restrict__ G, float* __restrict__ rs_t,
    float* __restrict__ csp, float* __restrict__ pm, float* __restrict__ ps) {
  __shared__ float redm[4][LT];
  __shared__ float reds[4][LT];
  int blk = blockIdx.x;
  int b = blk >> 2, ch = blk & 3;
  int w = threadIdx.x >> 6, lane = threadIdx.x & 63;
  const ushort* g = G + (size_t)b * LI * LT;
  int i0 = ch * 144;
  float c0 = 0.f, c1 = 0.f, c2 = 0.f, c3 = 0.f;
  float m0 = -1e30f, m1 = -1e30f, m2 = -1e30f, m3 = -1e30f;
  float s0 = 0.f, s1 = 0.f, s2 = 0.f, s3 = 0.f;
  for (int k = 0; k < 36; ++k) {
    int i = i0 + k * 4 + w;
    ushort4 u = reinterpret_cast<const ushort4*>(g + (size_t)i * LT)[lane];
    float r0 = fmaxf(b2f(u.x), 0.f), r1 = fmaxf(b2f(u.y), 0.f);
    float r2 = fmaxf(b2f(u.z), 0.f), r3 = fmaxf(b2f(u.w), 0.f);
    c0 += r0; c1 += r1; c2 += r2; c3 += r3;
    float s = r0 + r1 + r2 + r3;
    #pragma unroll
    for (int off = 32; off > 0; off >>= 1) s += __shfl_xor(s, off);
    if (lane == 0) rs_t[b * LI + i] = s;
    float inv = SMOOTHF / (s + EPSF);
    float x0 = r0 * inv, x1 = r1 * inv, x2 = r2 * inv, x3 = r3 * inv;
    float mn;
    mn = fmaxf(m0, x0); s0 = s0 * __expf(m0 - mn) + __expf(x0 - mn); m0 = mn;
    mn = fmaxf(m1, x1); s1 = s1 * __expf(m1 - mn) + __expf(x1 - mn); m1 = mn;
    mn = fmaxf(m2, x2); s2 = s2 * __expf(m2 - mn) + __expf(x2 - mn); m2 = mn;
    mn = fmaxf(m3, x3); s3 = s3 * __expf(m3 - mn) + __expf(x3 - mn); m3 = mn;
  }
  int t = threadIdx.x;
  redm[w][lane * 4 + 0] = c0; redm[w][lane * 4 + 1] = c1;
  redm[w][lane * 4 + 2] = c2; redm[w][lane * 4 + 3] = c3;
  __syncthreads();
  csp[(size_t)blk * LT + t] = redm[0][t] + redm[1][t] + redm[2][t] + redm[3][t];
  __syncthreads();
  redm[w][lane * 4 + 0] = m0; redm[w][lane * 4 + 1] = m1;
  redm[w][lane * 4 + 2] = m2; redm[w][lane * 4 + 3] = m3;
  reds[w][lane * 4 + 0] = s0; reds[w][lane * 4 + 1] = s1;
  reds[w][lane * 4 + 2] = s2; reds[w][lane * 4 + 3] = s3;
  __syncthreads();
  float mm = fmaxf(fmaxf(redm[0][t], redm[1][t]), fmaxf(redm[2][t], redm[3][t]));
  float ss = reds[0][t] * __expf(redm[0][t] - mm) + reds[1][t] * __expf(redm[1][t] - mm)
           + reds[2][t] * __expf(redm[2][t] - mm) + reds[3][t] * __expf(redm[3][t] - mm);
  pm[(size_t)blk * LT + t] = mm;
  ps[(size_t)blk * LT + t] = ss;
}

// ---------------- fused pass2 (+inline combine): attn_txt + attn_img --------
__global__ __launch_bounds__(256) void attn_fused_kernel(
    const ushort* __restrict__ G, const float* __restrict__ rs_t,
    const float* __restrict__ csp, const float* __restrict__ pm,
    const float* __restrict__ ps,
    float* __restrict__ at_f32, ushort* __restrict__ at_b16,
    float* __restrict__ ai_f32, ushort* __restrict__ ai_b16) {
  __shared__ ushort Gs[64][264];
  __shared__ float  T[64][65];
  __shared__ float  invl_s[64];
  __shared__ float  rsi_s[LT], mi_s[LT], si_s[LT];
  int b = blockIdx.y, i0 = blockIdx.x * 64;
  int q = threadIdx.x;
  { // inline combine: thread q owns t=q (redundant per block; trivial cost)
    float cs = 0.f, m = -1e30f, pv[4];
    #pragma unroll
    for (int c4 = 0; c4 < 4; ++c4) {
      cs += csp[(size_t)(b * 4 + c4) * LT + q];
      pv[c4] = pm[(size_t)(b * 4 + c4) * LT + q];
      m = fmaxf(m, pv[c4]);
    }
    float s = 0.f;
    #pragma unroll
    for (int c4 = 0; c4 < 4; ++c4)
      s += ps[(size_t)(b * 4 + c4) * LT + q] * __expf(pv[c4] - m);
    rsi_s[q] = SMOOTHF / (cs + EPSF);
    mi_s[q]  = m;
    si_s[q]  = 1.0f / s;
  }
  { // load tile: rows coalesced
    int row = q >> 2, c0 = (q & 3) * 64;
    const ushort* src = G + ((size_t)b * LI + i0 + row) * LT + c0;
    #pragma unroll
    for (int e = 0; e < 8; ++e) {
      uint4 v = *reinterpret_cast<const uint4*>(src + e * 8);
      *reinterpret_cast<uint4*>(&Gs[row][c0 + e * 8]) = v;
    }
  }
  if (q < 64) invl_s[q] = SMOOTHF / (rs_t[b * LI + i0 + q] + EPSF);
  __syncthreads();

  // ---- phase A: attn_txt (row softmax over t) ----
  {
    int w = q >> 6, lane = q & 63;
    float i0d = rsi_s[lane * 4 + 0], i1d = rsi_s[lane * 4 + 1];
    float i2d = rsi_s[lane * 4 + 2], i3d = rsi_s[lane * 4 + 3];
    #pragma unroll 4
    for (int rr = 0; rr < 16; ++rr) {
      int row = w * 16 + rr;
      ushort4 gu = *reinterpret_cast<const ushort4*>(&Gs[row][lane * 4]);
      float x0 = fmaxf(b2f(gu.x), 0.f) * i0d;
      float x1 = fmaxf(b2f(gu.y), 0.f) * i1d;
      float x2 = fmaxf(b2f(gu.z), 0.f) * i2d;
      float x3 = fmaxf(b2f(gu.w), 0.f) * i3d;
      float m = fmaxf(fmaxf(x0, x1), fmaxf(x2, x3));
      #pragma unroll
      for (int off = 32; off > 0; off >>= 1) m = fmaxf(m, __shfl_xor(m, off));
      float e0 = __expf(x0 - m), e1 = __expf(x1 - m);
      float e2 = __expf(x2 - m), e3 = __expf(x3 - m);
      float s = e0 + e1 + e2 + e3;
      #pragma unroll
      for (int off = 32; off > 0; off >>= 1) s += __shfl_xor(s, off);
      float inv = 1.0f / s;
      float4 o = make_float4(e0 * inv, e1 * inv, e2 * inv, e3 * inv);
      size_t roff = ((size_t)b * LI + i0 + row) * LT;
      reinterpret_cast<float4*>(at_f32 + roff)[lane] = o;
      reinterpret_cast<ushort4*>(at_b16 + roff)[lane] =
          make_ushort4(f2b(o.x), f2b(o.y), f2b(o.z), f2b(o.w));
    }
  }

  // ---- phase B: attn_img, 4 x (64t x 64i) transposed subtiles ----
  for (int tt = 0; tt < 4; ++tt) {
    __syncthreads();
    {
      int row = q >> 2;
      int t4  = (q & 3) * 16;
      float invl = invl_s[row];
      float mt[16], ist[16];
      #pragma unroll
      for (int e = 0; e < 16; ++e) {
        mt[e]  = mi_s[tt * 64 + t4 + e];
        ist[e] = si_s[tt * 64 + t4 + e];
      }
      #pragma unroll
      for (int u = 0; u < 2; ++u) {
        ushort gu[8];
        *reinterpret_cast<uint4*>(gu) =
            *reinterpret_cast<const uint4*>(&Gs[row][tt * 64 + t4 + u * 8]);
        #pragma unroll
        for (int e = 0; e < 8; ++e) {
          int idx = u * 8 + e;
          float x = fmaxf(b2f(gu[e]), 0.f) * invl;
          T[t4 + idx][row] = __expf(x - mt[idx]) * ist[idx];
        }
      }
    }
    __syncthreads();
    {
      int trow = q >> 2;
      int i4   = (q & 3) * 16;
      size_t off = ((size_t)b * LT + tt * 64 + trow) * LI + i0 + i4;
      #pragma unroll
      for (int e4 = 0; e4 < 4; ++e4) {
        float4 o = make_float4(T[trow][i4 + e4 * 4], T[trow][i4 + e4 * 4 + 1],
                               T[trow][i4 + e4 * 4 + 2], T[trow][i4 + e4 * 4 + 3]);
        *reinterpret_cast<float4*>(ai_f32 + off + e4 * 4) = o;
        reinterpret_cast<ushort4*>(ai_b16 + off)[e4] =
            make_ushort4(f2b(o.x), f2b(o.y), f2b(o.z), f2b(o.w));
      }
    }
  }
}

// ---------------- launch ----------------
extern "C" void kernel_launch(void* const* d_in, const int* in_sizes, int n_in,
                              void* d_out, int out_size, void* d_ws, size_t ws_size,
                              hipStream_t stream) {
  const float* txt   = (const float*)d_in[0];
  const float* img   = (const float*)d_in[1];
  const float* W_txt = (const float*)d_in[2];
  const float* b_txt = (const float*)d_in[3];
  const float* W_img = (const float*)d_in[4];
  const float* b_img = (const float*)d_in[5];

  float* out          = (float*)d_out;
  float* out_txt      = out;
  float* out_img      = out + (size_t)B_ * LT * HD;
  float* out_attn_img = out_img + (size_t)B_ * LI * HD;
  float* out_attn_txt = out_attn_img + (size_t)B_ * LT * LI;

  char* w = (char*)d_ws;
  auto alloc = [&](size_t bytes) -> char* {
    char* p = w; w += (bytes + 255) & ~(size_t)255; return p;
  };
  ushort* txt_b  = (ushort*)alloc((size_t)B_ * LT * HD * 2);
  ushort* img_b  = (ushort*)alloc((size_t)B_ * LI * HD * 2);
  ushort* imgT_b = (ushort*)alloc((size_t)B_ * HD * LI * 2);
  ushort* Wt_b   = (ushort*)alloc((size_t)HD * HD * 2);
  ushort* Wi_b   = (ushort*)alloc((size_t)HD * HD * 2);
  ushort* Gm_b   = (ushort*)alloc((size_t)B_ * LI * LT * 2);
  float*  rs_t   = (float*) alloc((size_t)B_ * LI * 4);
  float*  csp    = (float*) alloc((size_t)B_ * 4 * LT * 4);
  float*  pm     = (float*) alloc((size_t)B_ * 4 * LT * 4);
  float*  ps     = (float*) alloc((size_t)B_ * 4 * LT * 4);
  ushort* ai_b   = (ushort*)alloc((size_t)B_ * LT * LI * 2);
  ushort* at_b   = (ushort*)alloc((size_t)B_ * LI * LT * 2);
  ushort* txtAE  = (ushort*)alloc((size_t)B_ * LT * HD * 2);
  ushort* Pt     = (ushort*)alloc((size_t)B_ * HD * LT * 2);   // W_img . txt^T  [b,o,t]
  (void)ws_size; (void)in_sizes; (void)n_in; (void)out_size;   // ~604 MB

  // bf16 conversions: txt+weights plain; img -> normal + transposed
  cvt3_bf16_kernel<<<2048, 256, 0, stream>>>(
      txt, txt_b, B_ * LT * HD / 4,
      W_txt, Wt_b, HD * HD / 4, W_img, Wi_b, HD * HD / 4);
  cvtT_kernel<<<dim3((LI / 64) * (HD / 64), B_), 256, 0, stream>>>(
      img, img_b, imgT_b, LI);

  // G (384) + Pt (512) in one launch, single body (896 blocks)
  g_pt_kernel<<<896, 512, 131072, stream>>>(img_b, txt_b, Wi_b, Gm_b, Pt);

  // pass1: rowsums + col partials + attn_img online stats (one G read)
  gstats_kernel<<<B_ * 4, 256, 0, stream>>>(Gm_b, rs_t, csp, pm, ps);

  // pass2 (+inline combine): attn_txt + attn_img outputs (one G read)
  attn_fused_kernel<<<dim3(LI / 64, B_), 256, 0, stream>>>(
      Gm_b, rs_t, csp, pm, ps, out_attn_txt, at_b, out_attn_img, ai_b);

  // AV1: txtAE = attn_img . img  (8-phase NT via imgT, K=576 odd-NT; 512 blocks)
  av1_kernel<<<512, 512, 131072, stream>>>(ai_b, imgT_b, txtAE);

  // FC1 (512) + out_img (1536) in one launch, single body (2048 blocks)
  fc_oi_kernel<<<2048, 512, 131072, stream>>>(
      txtAE, Wt_b, b_txt, out_txt, at_b, Pt, b_img, out_img);
}

// Round 16
// 674.609 us; speedup vs baseline: 1.1758x; 1.1758x over previous
//
#include <hip/hip_runtime.h>
#include <hip/hip_bf16.h>
#include <stdint.h>

#define B_   128
#define LT   256
#define LI   576
#define HD   1024
#define SMOOTHF 9.0f
#define EPSF 1e-8f

typedef __bf16 bf16x8 __attribute__((ext_vector_type(8)));
typedef float  f32x4  __attribute__((ext_vector_type(4)));

__device__ inline ushort f2b(float f) {
  uint32_t u = __float_as_uint(f);
  u += 0x7FFFu + ((u >> 16) & 1u);   // RNE
  return (ushort)(u >> 16);
}
__device__ inline float b2f(ushort u) {
  return __uint_as_float((uint32_t)u << 16);
}

// async global->LDS, 16B per lane. LDS dest is wave-uniform base + lane*16.
__device__ __forceinline__ void gload_lds16(const ushort* g, ushort* l) {
  __builtin_amdgcn_global_load_lds(
      (const __attribute__((address_space(1))) unsigned int*)(g),
      (__attribute__((address_space(3))) unsigned int*)(l),
      16, 0, 0);
}

// ---------------- fp32 -> bf16, three ranges per launch ----------------
__global__ __launch_bounds__(256) void cvt3_bf16_kernel(
    const float* __restrict__ inA, ushort* __restrict__ outA, int n4A,
    const float* __restrict__ inB, ushort* __restrict__ outB, int n4B,
    const float* __restrict__ inC, ushort* __restrict__ outC, int n4C) {
  int idx = blockIdx.x * blockDim.x + threadIdx.x;
  int stride = gridDim.x * blockDim.x;
  int total = n4A + n4B + n4C;
  for (int i = idx; i < total; i += stride) {
    const float* in; ushort* out; int j;
    if (i < n4A)            { in = inA; out = outA; j = i; }
    else if (i < n4A + n4B) { in = inB; out = outB; j = i - n4A; }
    else                    { in = inC; out = outC; j = i - n4A - n4B; }
    float4 v = reinterpret_cast<const float4*>(in)[j];
    ushort4 o = make_ushort4(f2b(v.x), f2b(v.y), f2b(v.z), f2b(v.w));
    reinterpret_cast<ushort4*>(out)[j] = o;
  }
}

// ---------------- fp32 -> bf16 normal + transposed copies (r4-verified) ------
__global__ __launch_bounds__(256) void cvtT_kernel(
    const float* __restrict__ in, ushort* __restrict__ outN,
    ushort* __restrict__ outT, int R) {
  __shared__ float T[64][65];
  int b = blockIdx.y;
  int nrt = R >> 6;
  int rt = blockIdx.x % nrt, ct = blockIdx.x / nrt;
  int r0 = rt << 6, c0 = ct << 6;
  const float* src = in + ((size_t)b * R + r0) * HD + c0;
  ushort* dN = outN + ((size_t)b * R + r0) * HD + c0;
  ushort* dT = outT + ((size_t)b * HD + c0) * R + r0;
  int tid = threadIdx.x;
  #pragma unroll
  for (int j = 0; j < 4; ++j) {
    int q = tid + j * 256;
    int row = q >> 4;
    int c4  = (q & 15) << 2;
    float4 v = *reinterpret_cast<const float4*>(src + (size_t)row * HD + c4);
    reinterpret_cast<ushort4*>(dN + (size_t)row * HD)[c4 >> 2] =
        make_ushort4(f2b(v.x), f2b(v.y), f2b(v.z), f2b(v.w));
    T[c4 + 0][row] = v.x;
    T[c4 + 1][row] = v.y;
    T[c4 + 2][row] = v.z;
    T[c4 + 3][row] = v.w;
  }
  __syncthreads();
  #pragma unroll
  for (int j = 0; j < 4; ++j) {
    int q = tid + j * 256;
    int crow = q >> 4;
    int r4   = (q & 15) << 2;
    ushort4 o = make_ushort4(f2b(T[crow][r4]), f2b(T[crow][r4 + 1]),
                             f2b(T[crow][r4 + 2]), f2b(T[crow][r4 + 3]));
    reinterpret_cast<ushort4*>(dT + (size_t)crow * R)[r4 >> 2] = o;
  }
}

// ---------------- 256x256, BK=64, 8-phase counted-vmcnt + LDS swizzle --------
// r12/r13/r14-verified schedule (race-clean; odd-NT tail HW-verified).
// ONE instantiation per __global__ kernel, ONE GEMM shape per launch.
// (r13+r15 lesson: two 8-phase bodies in one kernel — whether two inlined
//  calls or compiler-specialized branches of one call — thrash the I$.)
template<bool MPRED, bool OUT_BF16, bool RELU_BIAS>
__global__ __launch_bounds__(512, 2)
void gemm256p8(const ushort* __restrict__ A, const ushort* __restrict__ Bm,
               const float* __restrict__ bias, void* __restrict__ C,
               int M, int N, int K, long sA, long sB, long sC,
               int lda, int ldb, int ldc)
{
  extern __shared__ ushort lds[];
  int bid = blockIdx.x;
  { int cpx = gridDim.x >> 3; bid = (bid & 7) * cpx + (bid >> 3); }
  const int ntn = N >> 8;
  const int ntm = (M + 255) >> 8;
  const int tpb = ntm * ntn;
  const int b   = bid / tpb;
  const int tl  = bid - b * tpb;
  const int m0 = (tl / ntn) << 8;
  const int n0 = (tl % ntn) << 8;

  const int t    = threadIdx.x;
  const int lane = t & 63, w = t >> 6;
  const int wr = w >> 2, wc = w & 3;          // quadrant-local: 2Mx4N waves
  const int r16 = lane & 15, g = lane >> 4;

  const ushort* gA0 = A  + (size_t)b * sA;
  const ushort* gB0 = Bm + (size_t)b * sB + (size_t)n0 * ldb;

  f32x4 acc[2][2][4][2] = {};
  const int NT  = K >> 6;
  const int NIT = NT >> 1;

  auto STAGEH = [&](int mat, int h, int kt) {
    ushort* dst = lds + (kt & 1) * 32768 + mat * 16384 + h * 8192 + t * 8;
    int scol = (((t & 7) ^ ((t >> 3) & 7)) << 3) + kt * 64;   // pre-swizzled src
    #pragma unroll
    for (int q = 0; q < 2; ++q) {
      int row = h * 128 + q * 64 + (t >> 3);
      const ushort* src;
      if (!mat) {
        int ar = m0 + row;
        if (MPRED) ar = ar < M ? ar : M - 1;
        src = gA0 + (size_t)ar * lda + scol;
      } else {
        src = gB0 + (size_t)row * ldb + scol;
      }
      gload_lds16(src, dst + q * 4096);
    }
  };

  // prologue: T0 complete + T1.A0,B0   (12 loads; vmcnt(4) -> T0 landed)
  STAGEH(0, 0, 0); STAGEH(1, 0, 0); STAGEH(0, 1, 0); STAGEH(1, 1, 0);
  STAGEH(0, 0, 1); STAGEH(1, 0, 1);
  asm volatile("s_waitcnt vmcnt(4)" ::: "memory");
  __builtin_amdgcn_sched_barrier(0);
  __builtin_amdgcn_s_barrier();
  __builtin_amdgcn_sched_barrier(0);

  const int sw = (r16 & 7) << 3;              // per-lane read swizzle

  for (int it = 0; it < NIT; ++it) {
    const int T0 = 2 * it;
    const bool lastit = (it == NIT - 1);
    #pragma unroll
    for (int p = 0; p < 8; ++p) {
      const int d  = p >> 2;
      const int qm = (p >> 1) & 1, qn = p & 1;
      const ushort* Ah = lds + d * 32768 + qm * 8192;
      const ushort* Bh = lds + d * 32768 + 16384 + qn * 8192;
      bf16x8 af[2][4], bfr[2][2];
      #pragma unroll
      for (int kk = 0; kk < 2; ++kk) {
        #pragma unroll
        for (int f = 0; f < 4; ++f)
          af[kk][f] = *reinterpret_cast<const bf16x8*>(
              Ah + (wr * 64 + f * 16 + r16) * 64 + ((kk * 32 + g * 8) ^ sw));
        #pragma unroll
        for (int c = 0; c < 2; ++c)
          bfr[kk][c] = *reinterpret_cast<const bf16x8*>(
              Bh + (wc * 32 + c * 16 + r16) * 64 + ((kk * 32 + g * 8) ^ sw));
      }
      {
        const int toff[8] = {1, 1, 2, 2, 2, 2, 3, 3};
        const int tmat[8] = {0, 1, 0, 1, 0, 1, 0, 1};
        const int thlf[8] = {1, 1, 0, 0, 1, 1, 0, 0};
        int kt = T0 + toff[p];
        if (kt < NT) STAGEH(tmat[p], thlf[p], kt);
      }
      if (p == 3 || p == 7) {
        if (lastit) { asm volatile("s_waitcnt vmcnt(0)" ::: "memory"); }
        else        { asm volatile("s_waitcnt vmcnt(4)" ::: "memory"); }
      }
      __builtin_amdgcn_sched_barrier(0);
      __builtin_amdgcn_s_barrier();
      __builtin_amdgcn_sched_barrier(0);
      __builtin_amdgcn_s_setprio(1);
      #pragma unroll
      for (int kk = 0; kk < 2; ++kk)
        #pragma unroll
        for (int f = 0; f < 4; ++f)
          #pragma unroll
          for (int c = 0; c < 2; ++c)
            acc[qm][qn][f][c] = __builtin_amdgcn_mfma_f32_16x16x32_bf16(
                af[kk][f], bfr[kk][c], acc[qm][qn][f][c], 0, 0, 0);
      __builtin_amdgcn_s_setprio(0);
      __builtin_amdgcn_sched_barrier(0);
      __builtin_amdgcn_s_barrier();
      __builtin_amdgcn_sched_barrier(0);
    }
  }

  // ---- odd-NT tail: last K-tile staged+drained at lastit; reads only ----
  if (NT & 1) {
    const int d = (NT - 1) & 1;
    const ushort* base = lds + d * 32768;
    #pragma unroll
    for (int p = 0; p < 4; ++p) {
      const int qm = p >> 1, qn = p & 1;
      const ushort* Ah = base + qm * 8192;
      const ushort* Bh = base + 16384 + qn * 8192;
      bf16x8 af[2][4], bfr[2][2];
      #pragma unroll
      for (int kk = 0; kk < 2; ++kk) {
        #pragma unroll
        for (int f = 0; f < 4; ++f)
          af[kk][f] = *reinterpret_cast<const bf16x8*>(
              Ah + (wr * 64 + f * 16 + r16) * 64 + ((kk * 32 + g * 8) ^ sw));
        #pragma unroll
        for (int c = 0; c < 2; ++c)
          bfr[kk][c] = *reinterpret_cast<const bf16x8*>(
              Bh + (wc * 32 + c * 16 + r16) * 64 + ((kk * 32 + g * 8) ^ sw));
      }
      #pragma unroll
      for (int kk = 0; kk < 2; ++kk)
        #pragma unroll
        for (int f = 0; f < 4; ++f)
          #pragma unroll
          for (int c = 0; c < 2; ++c)
            acc[qm][qn][f][c] = __builtin_amdgcn_mfma_f32_16x16x32_bf16(
                af[kk][f], bfr[kk][c], acc[qm][qn][f][c], 0, 0, 0);
    }
  }

  // epilogue: C/D layout col=lane&15, row=(lane>>4)*4+reg [m89-verified]
  #pragma unroll
  for (int qm = 0; qm < 2; ++qm)
    #pragma unroll
    for (int qn = 0; qn < 2; ++qn)
      #pragma unroll
      for (int f = 0; f < 4; ++f) {
        int rbase = m0 + qm * 128 + wr * 64 + f * 16 + g * 4;
        #pragma unroll
        for (int rr = 0; rr < 4; ++rr) {
          if (MPRED && (rbase + rr >= M)) continue;
          size_t off0 = (size_t)b * sC + (size_t)(rbase + rr) * ldc
                      + n0 + qn * 128 + wc * 32;
          #pragma unroll
          for (int c = 0; c < 2; ++c) {
            int col = c * 16 + r16;
            float v = acc[qm][qn][f][c][rr];
            if (RELU_BIAS) v = fmaxf(v + bias[n0 + qn * 128 + wc * 32 + col], 0.0f);
            if (OUT_BF16) reinterpret_cast<ushort*>(C)[off0 + col] = f2b(v);
            else          reinterpret_cast<float*>(C)[off0 + col]  = v;
          }
        }
      }
}

// ---------------- fused pass1: rowsums + col partials + attn_img stats --------
__global__ __launch_bounds__(256) void gstats_kernel(
    const ushort* __restrict__ G, float* __restrict__ rs_t,
    float* __restrict__ csp, float* __restrict__ pm, float* __restrict__ ps) {
  __shared__ float redm[4][LT];
  __shared__ float reds[4][LT];
  int blk = blockIdx.x;
  int b = blk >> 2, ch = blk & 3;
  int w = threadIdx.x >> 6, lane = threadIdx.x & 63;
  const ushort* g = G + (size_t)b * LI * LT;
  int i0 = ch * 144;
  float c0 = 0.f, c1 = 0.f, c2 = 0.f, c3 = 0.f;
  float m0 = -1e30f, m1 = -1e30f, m2 = -1e30f, m3 = -1e30f;
  float s0 = 0.f, s1 = 0.f, s2 = 0.f, s3 = 0.f;
  for (int k = 0; k < 36; ++k) {
    int i = i0 + k * 4 + w;
    ushort4 u = reinterpret_cast<const ushort4*>(g + (size_t)i * LT)[lane];
    float r0 = fmaxf(b2f(u.x), 0.f), r1 = fmaxf(b2f(u.y), 0.f);
    float r2 = fmaxf(b2f(u.z), 0.f), r3 = fmaxf(b2f(u.w), 0.f);
    c0 += r0; c1 += r1; c2 += r2; c3 += r3;
    float s = r0 + r1 + r2 + r3;
    #pragma unroll
    for (int off = 32; off > 0; off >>= 1) s += __shfl_xor(s, off);
    if (lane == 0) rs_t[b * LI + i] = s;
    float inv = SMOOTHF / (s + EPSF);
    float x0 = r0 * inv, x1 = r1 * inv, x2 = r2 * inv, x3 = r3 * inv;
    float mn;
    mn = fmaxf(m0, x0); s0 = s0 * __expf(m0 - mn) + __expf(x0 - mn); m0 = mn;
    mn = fmaxf(m1, x1); s1 = s1 * __expf(m1 - mn) + __expf(x1 - mn); m1 = mn;
    mn = fmaxf(m2, x2); s2 = s2 * __expf(m2 - mn) + __expf(x2 - mn); m2 = mn;
    mn = fmaxf(m3, x3); s3 = s3 * __expf(m3 - mn) + __expf(x3 - mn); m3 = mn;
  }
  int t = threadIdx.x;
  redm[w][lane * 4 + 0] = c0; redm[w][lane * 4 + 1] = c1;
  redm[w][lane * 4 + 2] = c2; redm[w][lane * 4 + 3] = c3;
  __syncthreads();
  csp[(size_t)blk * LT + t] = redm[0][t] + redm[1][t] + redm[2][t] + redm[3][t];
  __syncthreads();
  redm[w][lane * 4 + 0] = m0; redm[w][lane * 4 + 1] = m1;
  redm[w][lane * 4 + 2] = m2; redm[w][lane * 4 + 3] = m3;
  reds[w][lane * 4 + 0] = s0; reds[w][lane * 4 + 1] = s1;
  reds[w][lane * 4 + 2] = s2; reds[w][lane * 4 + 3] = s3;
  __syncthreads();
  float mm = fmaxf(fmaxf(redm[0][t], redm[1][t]), fmaxf(redm[2][t], redm[3][t]));
  float ss = reds[0][t] * __expf(redm[0][t] - mm) + reds[1][t] * __expf(redm[1][t] - mm)
           + reds[2][t] * __expf(redm[2][t] - mm) + reds[3][t] * __expf(redm[3][t] - mm);
  pm[(size_t)blk * LT + t] = mm;
  ps[(size_t)blk * LT + t] = ss;
}

// ---------------- fused pass2 (+inline combine): attn_txt + attn_img --------
__global__ __launch_bounds__(256) void attn_fused_kernel(
    const ushort* __restrict__ G, const float* __restrict__ rs_t,
    const float* __restrict__ csp, const float* __restrict__ pm,
    const float* __restrict__ ps,
    float* __restrict__ at_f32, ushort* __restrict__ at_b16,
    float* __restrict__ ai_f32, ushort* __restrict__ ai_b16) {
  __shared__ ushort Gs[64][264];
  __shared__ float  T[64][65];
  __shared__ float  invl_s[64];
  __shared__ float  rsi_s[LT], mi_s[LT], si_s[LT];
  int b = blockIdx.y, i0 = blockIdx.x * 64;
  int q = threadIdx.x;
  { // inline combine: thread q owns t=q (redundant per block; trivial cost)
    float cs = 0.f, m = -1e30f, pv[4];
    #pragma unroll
    for (int c4 = 0; c4 < 4; ++c4) {
      cs += csp[(size_t)(b * 4 + c4) * LT + q];
      pv[c4] = pm[(size_t)(b * 4 + c4) * LT + q];
      m = fmaxf(m, pv[c4]);
    }
    float s = 0.f;
    #pragma unroll
    for (int c4 = 0; c4 < 4; ++c4)
      s += ps[(size_t)(b * 4 + c4) * LT + q] * __expf(pv[c4] - m);
    rsi_s[q] = SMOOTHF / (cs + EPSF);
    mi_s[q]  = m;
    si_s[q]  = 1.0f / s;
  }
  { // load tile: rows coalesced
    int row = q >> 2, c0 = (q & 3) * 64;
    const ushort* src = G + ((size_t)b * LI + i0 + row) * LT + c0;
    #pragma unroll
    for (int e = 0; e < 8; ++e) {
      uint4 v = *reinterpret_cast<const uint4*>(src + e * 8);
      *reinterpret_cast<uint4*>(&Gs[row][c0 + e * 8]) = v;
    }
  }
  if (q < 64) invl_s[q] = SMOOTHF / (rs_t[b * LI + i0 + q] + EPSF);
  __syncthreads();

  // ---- phase A: attn_txt (row softmax over t) ----
  {
    int w = q >> 6, lane = q & 63;
    float i0d = rsi_s[lane * 4 + 0], i1d = rsi_s[lane * 4 + 1];
    float i2d = rsi_s[lane * 4 + 2], i3d = rsi_s[lane * 4 + 3];
    #pragma unroll 4
    for (int rr = 0; rr < 16; ++rr) {
      int row = w * 16 + rr;
      ushort4 gu = *reinterpret_cast<const ushort4*>(&Gs[row][lane * 4]);
      float x0 = fmaxf(b2f(gu.x), 0.f) * i0d;
      float x1 = fmaxf(b2f(gu.y), 0.f) * i1d;
      float x2 = fmaxf(b2f(gu.z), 0.f) * i2d;
      float x3 = fmaxf(b2f(gu.w), 0.f) * i3d;
      float m = fmaxf(fmaxf(x0, x1), fmaxf(x2, x3));
      #pragma unroll
      for (int off = 32; off > 0; off >>= 1) m = fmaxf(m, __shfl_xor(m, off));
      float e0 = __expf(x0 - m), e1 = __expf(x1 - m);
      float e2 = __expf(x2 - m), e3 = __expf(x3 - m);
      float s = e0 + e1 + e2 + e3;
      #pragma unroll
      for (int off = 32; off > 0; off >>= 1) s += __shfl_xor(s, off);
      float inv = 1.0f / s;
      float4 o = make_float4(e0 * inv, e1 * inv, e2 * inv, e3 * inv);
      size_t roff = ((size_t)b * LI + i0 + row) * LT;
      reinterpret_cast<float4*>(at_f32 + roff)[lane] = o;
      reinterpret_cast<ushort4*>(at_b16 + roff)[lane] =
          make_ushort4(f2b(o.x), f2b(o.y), f2b(o.z), f2b(o.w));
    }
  }

  // ---- phase B: attn_img, 4 x (64t x 64i) transposed subtiles ----
  for (int tt = 0; tt < 4; ++tt) {
    __syncthreads();
    {
      int row = q >> 2;
      int t4  = (q & 3) * 16;
      float invl = invl_s[row];
      float mt[16], ist[16];
      #pragma unroll
      for (int e = 0; e < 16; ++e) {
        mt[e]  = mi_s[tt * 64 + t4 + e];
        ist[e] = si_s[tt * 64 + t4 + e];
      }
      #pragma unroll
      for (int u = 0; u < 2; ++u) {
        ushort gu[8];
        *reinterpret_cast<uint4*>(gu) =
            *reinterpret_cast<const uint4*>(&Gs[row][tt * 64 + t4 + u * 8]);
        #pragma unroll
        for (int e = 0; e < 8; ++e) {
          int idx = u * 8 + e;
          float x = fmaxf(b2f(gu[e]), 0.f) * invl;
          T[t4 + idx][row] = __expf(x - mt[idx]) * ist[idx];
        }
      }
    }
    __syncthreads();
    {
      int trow = q >> 2;
      int i4   = (q & 3) * 16;
      size_t off = ((size_t)b * LT + tt * 64 + trow) * LI + i0 + i4;
      #pragma unroll
      for (int e4 = 0; e4 < 4; ++e4) {
        float4 o = make_float4(T[trow][i4 + e4 * 4], T[trow][i4 + e4 * 4 + 1],
                               T[trow][i4 + e4 * 4 + 2], T[trow][i4 + e4 * 4 + 3]);
        *reinterpret_cast<float4*>(ai_f32 + off + e4 * 4) = o;
        reinterpret_cast<ushort4*>(ai_b16 + off)[e4] =
            make_ushort4(f2b(o.x), f2b(o.y), f2b(o.z), f2b(o.w));
      }
    }
  }
}

// ---------------- launch ----------------
extern "C" void kernel_launch(void* const* d_in, const int* in_sizes, int n_in,
                              void* d_out, int out_size, void* d_ws, size_t ws_size,
                              hipStream_t stream) {
  const float* txt   = (const float*)d_in[0];
  const float* img   = (const float*)d_in[1];
  const float* W_txt = (const float*)d_in[2];
  const float* b_txt = (const float*)d_in[3];
  const float* W_img = (const float*)d_in[4];
  const float* b_img = (const float*)d_in[5];

  float* out          = (float*)d_out;
  float* out_txt      = out;
  float* out_img      = out + (size_t)B_ * LT * HD;
  float* out_attn_img = out_img + (size_t)B_ * LI * HD;
  float* out_attn_txt = out_attn_img + (size_t)B_ * LT * LI;

  char* w = (char*)d_ws;
  auto alloc = [&](size_t bytes) -> char* {
    char* p = w; w += (bytes + 255) & ~(size_t)255; return p;
  };
  ushort* txt_b  = (ushort*)alloc((size_t)B_ * LT * HD * 2);
  ushort* img_b  = (ushort*)alloc((size_t)B_ * LI * HD * 2);
  ushort* imgT_b = (ushort*)alloc((size_t)B_ * HD * LI * 2);
  ushort* Wt_b   = (ushort*)alloc((size_t)HD * HD * 2);
  ushort* Wi_b   = (ushort*)alloc((size_t)HD * HD * 2);
  ushort* Gm_b   = (ushort*)alloc((size_t)B_ * LI * LT * 2);
  float*  rs_t   = (float*) alloc((size_t)B_ * LI * 4);
  float*  csp    = (float*) alloc((size_t)B_ * 4 * LT * 4);
  float*  pm     = (float*) alloc((size_t)B_ * 4 * LT * 4);
  float*  ps     = (float*) alloc((size_t)B_ * 4 * LT * 4);
  ushort* ai_b   = (ushort*)alloc((size_t)B_ * LT * LI * 2);
  ushort* at_b   = (ushort*)alloc((size_t)B_ * LI * LT * 2);
  ushort* txtAE  = (ushort*)alloc((size_t)B_ * LT * HD * 2);
  ushort* Pt     = (ushort*)alloc((size_t)B_ * HD * LT * 2);   // W_img . txt^T  [b,o,t]
  (void)ws_size; (void)in_sizes; (void)n_in; (void)out_size;   // ~604 MB

  // bf16 conversions: txt+weights plain; img -> normal + transposed
  cvt3_bf16_kernel<<<2048, 256, 0, stream>>>(
      txt, txt_b, B_ * LT * HD / 4,
      W_txt, Wt_b, HD * HD / 4, W_img, Wi_b, HD * HD / 4);
  cvtT_kernel<<<dim3((LI / 64) * (HD / 64), B_), 256, 0, stream>>>(
      img, img_b, imgT_b, LI);

  // G[b,i,t] = img.txt^T  -> bf16  (8-phase, MPRED M=576; 384 blocks)
  gemm256p8<true, true, false><<<B_ * 3, 512, 131072, stream>>>(
      img_b, txt_b, nullptr, Gm_b, LI, LT, HD,
      (long)LI * HD, (long)LT * HD, (long)LI * LT, HD, HD, LT);

  // Pt[b,o,t] = W_img . txt[b]^T  (8-phase batched NT; 512 blocks)
  gemm256p8<false, true, false><<<B_ * (HD / 256) * (LT / 256), 512, 131072, stream>>>(
      Wi_b, txt_b, nullptr, Pt, HD, LT, HD,
      0L, (long)LT * HD, (long)HD * LT, HD, HD, LT);

  // pass1: rowsums + col partials + attn_img online stats (one G read)
  gstats_kernel<<<B_ * 4, 256, 0, stream>>>(Gm_b, rs_t, csp, pm, ps);

  // pass2 (+inline combine): attn_txt + attn_img outputs (one G read)
  attn_fused_kernel<<<dim3(LI / 64, B_), 256, 0, stream>>>(
      Gm_b, rs_t, csp, pm, ps, out_attn_txt, at_b, out_attn_img, ai_b);

  // AV1: txtAE = attn_img . img  (8-phase NT via imgT, K=576 odd-NT; 512 blocks)
  gemm256p8<false, true, false><<<B_ * (LT / 256) * (HD / 256), 512, 131072, stream>>>(
      ai_b, imgT_b, nullptr, txtAE, LT, HD, LI,
      (long)LT * LI, (long)HD * LI, (long)LT * HD, LI, LI, HD);

  // FC1: out_txt = relu(txtAE @ W_txt^T + b)  (8-phase flattened; 512 blocks)
  gemm256p8<false, false, true><<<(B_ * LT / 256) * (HD / 256), 512, 131072, stream>>>(
      txtAE, Wt_b, b_txt, out_txt, B_ * LT, HD, HD,
      0L, 0L, 0L, HD, HD, HD);

  // out_img = relu(attn_txt . Pt[b]^T + b_img)  (8-phase MPRED, K=256; 1536 blocks)
  gemm256p8<true, false, true><<<B_ * 3 * (HD / 256), 512, 131072, stream>>>(
      at_b, Pt, b_img, out_img, LI, HD, LT,
      (long)LI * LT, (long)HD * LT, (long)LI * HD, LT, LT, HD);
}